// Round 8
// baseline (2712.058 us; speedup 1.0000x reference)
//
#include <hip/hip_runtime.h>

// DeepSeekV2 MoE gate — fp32 VALU GEMM, BIT-IDENTICAL arithmetic to the
// passing round-1/round-5 kernels (per (t,e): 80 K-tiles of 64 sequential
// fmafs in ascending kk, tile partials accumulated in kt order).
// Round-8 data-movement restructure:
//   - staging via __builtin_amdgcn_global_load_lds width=16 (zero staging
//     registers, no ds_writes): As[32][64], Bs[160][64] fp32, LDS-linear dest
//   - B conflict-free by PRE-SWIZZLED GLOBAL SOURCE (m173 / rule #21):
//     source col chunk = (l&15) ^ (e&7); reads use the same XOR -> ds_read_b128
//     bank-quads perfectly spread (4 addrs/quad = data floor). A is broadcast.
//   - TOKB=32 -> grid 512 = 2 blocks/CU: the other block's compute hides this
//     block's vmcnt(0)+barrier drain (m114 overlap). LDS 48KB/block.
// Epilogue (softmax + grouped top-3/top-6) is round-1's code verbatim.
// Outputs (float32): [0..T*6) = topk_idx as float, [T*6..2*T*6) = weight.

#define NT    16384
#define HID   5120
#define NEXP  160
#define TOKB  32
#define NKT   80               // K tiles of 64
#define S_S   164              // epilogue score row stride

typedef const __attribute__((address_space(1))) void GAS;
typedef __attribute__((address_space(3))) void LAS;
#define GLOAD16(gp, lp) \
    __builtin_amdgcn_global_load_lds((GAS*)(gp), (LAS*)(lp), 16, 0, 0)

__global__ __launch_bounds__(256)
void moe_gate_kernel(const float* __restrict__ X,
                     const float* __restrict__ W,
                     float* __restrict__ out)
{
    // GEMM staging (49152 B) and epilogue scores (20992 B) share LDS.
    __shared__ union alignas(16) SM {
        struct { float As[TOKB * 64]; float Bs[NEXP * 64]; } g;
        float S[TOKB][S_S];
    } u;

    const int tid = threadIdx.x;
    const int tx  = tid & 31;      // expert lane: experts tx + 32q, q=0..4
    const int grp = tid >> 5;      // token group: tokens 4*grp .. 4*grp+3
    const int l   = tid & 63;
    const int w   = tid >> 6;      // wave 0..3
    const int tb  = blockIdx.x * TOKB;

    // ---- per-lane staging sources (12 x 1KB chunks per wave) ----
    // As chunk jA=2w+jj: rows r=4*jA+(l>>4); linear source (A reads broadcast).
    const float* srcA[2];
    #pragma unroll
    for (int jj = 0; jj < 2; ++jj) {
        const int r = 4 * (2 * w + jj) + (l >> 4);
        srcA[jj] = X + (size_t)(tb + r) * HID + 4 * (l & 15);
    }
    // Bs chunk jB=10w+m: rows e=4*jB+(l>>4); source col chunk (l&15)^(e&7).
    const float* srcB[10];
    #pragma unroll
    for (int m = 0; m < 10; ++m) {
        const int e = 4 * (10 * w + m) + (l >> 4);
        srcB[m] = W + (size_t)e * HID + 4 * ((l & 15) ^ (e & 7));
    }
    char* ldsA = (char*)&u.g.As[0] + (size_t)(2 * w) * 1024;
    char* ldsB = (char*)&u.g.Bs[0] + (size_t)(10 * w) * 1024;

    auto ISSUE = [&](int kt) {
        #pragma unroll
        for (int jj = 0; jj < 2; ++jj)
            GLOAD16(srcA[jj] + kt * 64, ldsA + jj * 1024);
        #pragma unroll
        for (int m = 0; m < 10; ++m)
            GLOAD16(srcB[m] + kt * 64, ldsB + m * 1024);
    };

    float acc[4][5];
    #pragma unroll
    for (int i = 0; i < 4; ++i)
        #pragma unroll
        for (int q = 0; q < 5; ++q) acc[i][q] = 0.f;

    const int   stx = tx & 7;
    const float* Ab = &u.g.As[(4 * grp) * 64];   // token rows 4grp..4grp+3
    const float* Bb = &u.g.Bs[tx * 64];          // + q*(32*64) per expert q

    ISSUE(0);

    for (int kt = 0; kt < NKT; ++kt) {
        asm volatile("s_waitcnt vmcnt(0)" ::: "memory");  // own loads arrived
        __syncthreads();                                  // tile complete

        float tacc[4][5];
        #pragma unroll
        for (int i = 0; i < 4; ++i)
            #pragma unroll
            for (int q = 0; q < 5; ++q) tacc[i][q] = 0.f;

        #pragma unroll
        for (int c = 0; c < 16; ++c) {       // kk quad = 4c..4c+3, ascending
            float4 Aq[4], Bq[5];
            #pragma unroll
            for (int i = 0; i < 4; ++i)      // broadcast reads, offset-folded
                Aq[i] = *(const float4*)(Ab + i * 64 + 4 * c);
            const int bo = 4 * (c ^ stx);    // swizzle-matched read offset
            #pragma unroll
            for (int q = 0; q < 5; ++q)
                Bq[q] = *(const float4*)(Bb + q * (32 * 64) + bo);
            #pragma unroll
            for (int i = 0; i < 4; ++i)
                #pragma unroll
                for (int q = 0; q < 5; ++q) {
                    tacc[i][q] = fmaf(Aq[i].x, Bq[q].x, tacc[i][q]);
                    tacc[i][q] = fmaf(Aq[i].y, Bq[q].y, tacc[i][q]);
                    tacc[i][q] = fmaf(Aq[i].z, Bq[q].z, tacc[i][q]);
                    tacc[i][q] = fmaf(Aq[i].w, Bq[q].w, tacc[i][q]);
                }
        }
        #pragma unroll
        for (int i = 0; i < 4; ++i)
            #pragma unroll
            for (int q = 0; q < 5; ++q) acc[i][q] += tacc[i][q];

        __syncthreads();                     // all waves done reading tile
        if (kt + 1 < NKT) ISSUE(kt + 1);     // refill (drains at next top)
    }

    // ---- write logits to the score buffer (token 4grp+i, expert tx+32q) ----
    #pragma unroll
    for (int i = 0; i < 4; ++i) {
        const int t = 4 * grp + i;
        #pragma unroll
        for (int q = 0; q < 5; ++q) u.S[t][tx + 32 * q] = acc[i][q];
    }
    __syncthreads();

    // ---- epilogue (round-1 verified): each wave owns 8 tokens ----
    const int lane = tid & 63;
    const int wv_  = tid >> 6;

    for (int it = 0; it < 8; ++it) {
        const int t = wv_ * 8 + it;

        float s0 = u.S[t][lane];
        float s1 = u.S[t][lane + 64];
        float s2 = (lane < 32) ? u.S[t][lane + 128] : -3.0e38f;

        float m = fmaxf(fmaxf(s0, s1), s2);
        #pragma unroll
        for (int d = 32; d >= 1; d >>= 1) m = fmaxf(m, __shfl_xor(m, d));

        float p0 = __expf(s0 - m);
        float p1 = __expf(s1 - m);
        float p2 = (lane < 32) ? __expf(s2 - m) : 0.f;
        float sum = p0 + p1 + p2;
        #pragma unroll
        for (int d = 32; d >= 1; d >>= 1) sum += __shfl_xor(sum, d);
        const float inv = 1.0f / sum;
        const float sc0 = p0 * inv, sc1 = p1 * inv, sc2 = p2 * inv;

        u.S[t][lane]      = sc0;
        u.S[t][lane + 64] = sc1;
        if (lane < 32) u.S[t][lane + 128] = sc2;
        __syncthreads();   // uniform across block (all waves loop 8x)

        float gm = -1.0f;
        if (lane < 8) {
            #pragma unroll
            for (int q = 0; q < 20; ++q) gm = fmaxf(gm, u.S[t][lane * 20 + q]);
        }
        unsigned gmask = 0u;
        {
            float gv[8];
            #pragma unroll
            for (int g = 0; g < 8; ++g) gv[g] = __shfl(gm, g);
            #pragma unroll
            for (int r = 0; r < 3; ++r) {
                int bi = 0; float bv2 = -2.0f;
                #pragma unroll
                for (int g = 0; g < 8; ++g) {
                    const bool taken = (gmask >> g) & 1u;
                    if (!taken && gv[g] > bv2) { bv2 = gv[g]; bi = g; }
                }
                gmask |= (1u << bi);
            }
        }

        float v0 = ((gmask >> (lane / 20)) & 1u) ? sc0 : 0.f;
        float v1 = ((gmask >> ((lane + 64) / 20)) & 1u) ? sc1 : 0.f;
        float v2 = (lane < 32) ? ((((gmask >> ((lane + 128) / 20)) & 1u) ? sc2 : 0.f))
                               : -1.f;

        float oIdx = 0.f, oW = 0.f;
        #pragma unroll
        for (int r = 0; r < 6; ++r) {
            float bv = v0; int bi = lane;
            if (v1 > bv) { bv = v1; bi = lane + 64; }
            if (v2 > bv) { bv = v2; bi = lane + 128; }
            #pragma unroll
            for (int d = 1; d < 64; d <<= 1) {
                const float ov = __shfl_xor(bv, d);
                const int   oi = __shfl_xor(bi, d);
                if (ov > bv || (ov == bv && oi < bi)) { bv = ov; bi = oi; }
            }
            if (lane == r) { oIdx = (float)bi; oW = bv * 16.0f; }
            if (bi == lane)            v0 = -1.f;
            else if (bi == lane + 64)  v1 = -1.f;
            else if (bi == lane + 128) v2 = -1.f;
        }

        const int tglob = tb + t;
        if (lane < 6) {
            out[(size_t)tglob * 6 + lane]                  = oIdx;
            out[(size_t)NT * 6 + (size_t)tglob * 6 + lane] = oW;
        }
        __syncthreads();
    }
}

extern "C" void kernel_launch(void* const* d_in, const int* in_sizes, int n_in,
                              void* d_out, int out_size, void* d_ws, size_t ws_size,
                              hipStream_t stream)
{
    const float* X = (const float*)d_in[0];   // [4,4096,5120] fp32
    const float* W = (const float*)d_in[1];   // [160,5120] fp32
    float* out = (float*)d_out;               // [T*6 idx][T*6 weight] fp32

    moe_gate_kernel<<<NT / TOKB, 256, 0, stream>>>(X, W, out);
}

// Round 9
// 813.489 us; speedup vs baseline: 3.3339x; 3.3339x over previous
//
#include <hip/hip_runtime.h>

// DeepSeekV2 MoE gate — fp32 VALU GEMM, BIT-IDENTICAL arithmetic to the
// passing round-1/round-5 kernels (per (t,e): 80 logical K-tiles of 64
// sequential fmafs in ascending kk, tile partials accumulated in kt order).
// Round-9 structure:
//   - block = 64 tokens, 512 thr (8 waves); wave = 20-expert band, lane = token
//     -> ALL B (W) LDS reads are wave-uniform broadcasts: zero conflicts,
//        no swizzle, 1 cyc each. Only A needs bank geometry.
//   - A via pre-swizzled global source (rule #21): LDS linear, src chunk
//     (l&7)^(row&7); read addr tok*32 + 4*(c^(tok&7)) -> 8-cyc 1KB data floor
//   - staging via global_load_lds width=16, K sub-tiles of 32, LDS
//     double-buffered (2x28KB), ONE barrier + implicit vmcnt(0) per sub-tile:
//     prefetch ISSUE(st+1) stays in flight across the whole compute phase
//   - tacc spans TWO sub-tiles (= one logical 64-k tile) before acc += tacc,
//     preserving R1's exact summation bracketing bit-for-bit
// Epilogue (softmax + grouped top-3/top-6) is round-1's code verbatim.
// Outputs (float32): [0..T*6) = topk_idx as float, [T*6..2*T*6) = weight.

#define NT    16384
#define HID   5120
#define NEXP  160
#define TOKB  64
#define NST   160              // K sub-tiles of 32 dwords
#define S_S   164              // epilogue score row stride

typedef const __attribute__((address_space(1))) void GAS;
typedef __attribute__((address_space(3))) void LAS;
#define GLOAD16(gp, lp) \
    __builtin_amdgcn_global_load_lds((GAS*)(gp), (LAS*)(lp), 16, 0, 0)

__global__ __launch_bounds__(512, 2)
void moe_gate_kernel(const float* __restrict__ X,
                     const float* __restrict__ W,
                     float* __restrict__ out)
{
    // double-buffered GEMM staging (57344 B) / epilogue scores (41984 B)
    __shared__ union alignas(16) SM {
        struct { float As[2][TOKB * 32]; float Bs[2][NEXP * 32]; } g;
        float S[TOKB][S_S];
    } u;

    const int tid = threadIdx.x;
    const int tok = tid & 63;          // lane = token
    const int w   = tid >> 6;          // wave = 20-expert band 20w..20w+19
    const int tk7 = tok & 7;
    const int tb  = blockIdx.x * TOKB;

    // ---- staging sources (1KB chunks: 8 rows x 32 dwords, lane l -> row
    //      8*instr+(l>>3), chunk l&7). A source pre-swizzled, B linear. ----
    const int rr = tok >> 3;           // row-in-chunk 0..7
    const int r8 = tok & 7;            // 16B chunk-in-row 0..7
    const float* srcA  = X + (size_t)(tb + 8 * w + rr) * HID + 4 * (r8 ^ rr);
    const float* srcB0 = W + (size_t)(8 * w + rr) * HID + 4 * r8;        // e=8w+rr
    const float* srcB1 = W + (size_t)(8 * w + 64 + rr) * HID + 4 * r8;   // +64
    const float* srcB2 = W + (size_t)(8 * w + 128 + rr) * HID + 4 * r8;  // +128 (w<4)

    auto ISSUE = [&](int st, int b) {
        const size_t ko = (size_t)st * 32;
        GLOAD16(srcA  + ko, &u.g.As[b][w * 256]);
        GLOAD16(srcB0 + ko, &u.g.Bs[b][w * 256]);
        GLOAD16(srcB1 + ko, &u.g.Bs[b][(w + 8) * 256]);
        if (w < 4) GLOAD16(srcB2 + ko, &u.g.Bs[b][(w + 16) * 256]);
    };

    float acc[20], tacc[20];
    #pragma unroll
    for (int j = 0; j < 20; ++j) acc[j] = 0.f;

    ISSUE(0, 0);

    for (int st = 0; st < NST; ++st) {
        const int b = st & 1;
        asm volatile("s_waitcnt vmcnt(0)" ::: "memory");  // this st's loads landed
        __syncthreads();                                  // tile visible block-wide
        if (st + 1 < NST) ISSUE(st + 1, b ^ 1);           // prefetch, in flight
                                                          //   across compute
        if (!(st & 1)) {
            #pragma unroll
            for (int j = 0; j < 20; ++j) tacc[j] = 0.f;   // new logical 64-k tile
        }

        const float* Ab = &u.g.As[b][(size_t)tok * 32];
        const float* Bb = &u.g.Bs[b][(size_t)w * 640];

        #pragma unroll 4
        for (int c = 0; c < 8; ++c) {                     // kk quad, ascending
            const float4 a = *(const float4*)(Ab + 4 * (c ^ tk7));
            #pragma unroll
            for (int j = 0; j < 20; ++j) {                // uniform -> broadcast
                const float4 bq = *(const float4*)(Bb + j * 32 + 4 * c);
                tacc[j] = fmaf(a.x, bq.x, tacc[j]);
                tacc[j] = fmaf(a.y, bq.y, tacc[j]);
                tacc[j] = fmaf(a.z, bq.z, tacc[j]);
                tacc[j] = fmaf(a.w, bq.w, tacc[j]);
            }
        }
        if (st & 1) {
            #pragma unroll
            for (int j = 0; j < 20; ++j) acc[j] += tacc[j];   // kt-order combine
        }
        // next top barrier doubles as the read/overwrite fence for buf b
    }

    // ---- write logits: token=lane, experts 20w..20w+19 ----
    __syncthreads();                   // all waves done with staging buffers
    #pragma unroll
    for (int j = 0; j < 20; ++j) u.S[tok][20 * w + j] = acc[j];
    __syncthreads();

    // ---- epilogue (round-1 verified): each of 8 waves owns 8 tokens ----
    const int lane = tid & 63;
    const int wv_  = tid >> 6;

    for (int it = 0; it < 8; ++it) {
        const int t = wv_ * 8 + it;

        float s0 = u.S[t][lane];
        float s1 = u.S[t][lane + 64];
        float s2 = (lane < 32) ? u.S[t][lane + 128] : -3.0e38f;

        float m = fmaxf(fmaxf(s0, s1), s2);
        #pragma unroll
        for (int d = 32; d >= 1; d >>= 1) m = fmaxf(m, __shfl_xor(m, d));

        float p0 = __expf(s0 - m);
        float p1 = __expf(s1 - m);
        float p2 = (lane < 32) ? __expf(s2 - m) : 0.f;
        float sum = p0 + p1 + p2;
        #pragma unroll
        for (int d = 32; d >= 1; d >>= 1) sum += __shfl_xor(sum, d);
        const float inv = 1.0f / sum;
        const float sc0 = p0 * inv, sc1 = p1 * inv, sc2 = p2 * inv;

        u.S[t][lane]      = sc0;
        u.S[t][lane + 64] = sc1;
        if (lane < 32) u.S[t][lane + 128] = sc2;
        __syncthreads();   // uniform across block (all waves loop 8x)

        float gm = -1.0f;
        if (lane < 8) {
            #pragma unroll
            for (int q = 0; q < 20; ++q) gm = fmaxf(gm, u.S[t][lane * 20 + q]);
        }
        unsigned gmask = 0u;
        {
            float gv[8];
            #pragma unroll
            for (int g = 0; g < 8; ++g) gv[g] = __shfl(gm, g);
            #pragma unroll
            for (int r = 0; r < 3; ++r) {
                int bi = 0; float bv2 = -2.0f;
                #pragma unroll
                for (int g = 0; g < 8; ++g) {
                    const bool taken = (gmask >> g) & 1u;
                    if (!taken && gv[g] > bv2) { bv2 = gv[g]; bi = g; }
                }
                gmask |= (1u << bi);
            }
        }

        float v0 = ((gmask >> (lane / 20)) & 1u) ? sc0 : 0.f;
        float v1 = ((gmask >> ((lane + 64) / 20)) & 1u) ? sc1 : 0.f;
        float v2 = (lane < 32) ? ((((gmask >> ((lane + 128) / 20)) & 1u) ? sc2 : 0.f))
                               : -1.f;

        float oIdx = 0.f, oW = 0.f;
        #pragma unroll
        for (int r = 0; r < 6; ++r) {
            float bv = v0; int bi = lane;
            if (v1 > bv) { bv = v1; bi = lane + 64; }
            if (v2 > bv) { bv = v2; bi = lane + 128; }
            #pragma unroll
            for (int d = 1; d < 64; d <<= 1) {
                const float ov = __shfl_xor(bv, d);
                const int   oi = __shfl_xor(bi, d);
                if (ov > bv || (ov == bv && oi < bi)) { bv = ov; bi = oi; }
            }
            if (lane == r) { oIdx = (float)bi; oW = bv * 16.0f; }
            if (bi == lane)            v0 = -1.f;
            else if (bi == lane + 64)  v1 = -1.f;
            else if (bi == lane + 128) v2 = -1.f;
        }

        const int tg = tb + t;
        if (lane < 6) {
            out[(size_t)tg * 6 + lane]                  = oIdx;
            out[(size_t)NT * 6 + (size_t)tg * 6 + lane] = oW;
        }
        __syncthreads();
    }
}

extern "C" void kernel_launch(void* const* d_in, const int* in_sizes, int n_in,
                              void* d_out, int out_size, void* d_ws, size_t ws_size,
                              hipStream_t stream)
{
    const float* X = (const float*)d_in[0];   // [4,4096,5120] fp32
    const float* W = (const float*)d_in[1];   // [160,5120] fp32
    float* out = (float*)d_out;               // [T*6 idx][T*6 weight] fp32

    moe_gate_kernel<<<NT / TOKB, 512, 0, stream>>>(X, W, out);
}

// Round 11
// 690.692 us; speedup vs baseline: 3.9266x; 1.1778x over previous
//
#include <hip/hip_runtime.h>

// DeepSeekV2 MoE gate — fp32 VALU GEMM, BIT-IDENTICAL arithmetic to the
// passing round-1/5/9 kernels (per (t,e): 80 logical 64-k tiles of sequential
// fmafs in ascending k, tile partials accumulated in kt order).
// Round-11 structure (R7's operand ratio + R9's staging, no staging regs):
//   - block = 64 tokens, 256 thr (4 waves); thread tile = 8 tok x 5 exp
//     -> per 4-k quad: 8 A-reads (2-addr broadcast, free) + 5 B-reads
//        (4-cyc data floor) per 160 FMA-instr: LDS pipe at ~54% of FMA wall
//   - staging via global_load_lds w=16 (R9-proven), SUBK=32, double-buffered
//     2x28KB; ONE barrier + vmcnt(0) per subtile, prefetch in flight across
//     the whole compute phase (2560 cyc >> 900 cyc HBM)
//   - B conflict-free by pre-swizzled global source: src slot (l&7)^(l>>3),
//     read slot c^(tx&7); A linear (reads are broadcasts)
//   - explicit 2-quad register ping-pong (named bufs = bounded live range;
//     R8's spill came from unbounded cross-quad scheduler pipelining)
//   - tacc spans two subtiles = one logical 64-k tile -> R1's exact bracket
// Epilogue (softmax + grouped top-3/top-6) is round-5's code verbatim.
// Outputs (float32): [0..T*6) = topk_idx as float, [T*6..2*T*6) = weight.

#define NT    16384
#define HID   5120
#define NEXP  160
#define TOKB  64
#define NST   160              // K sub-tiles of 32 dwords
#define S_S   164              // epilogue score row stride

typedef __attribute__((ext_vector_type(4))) float f32x4;

typedef const __attribute__((address_space(1))) void GAS;
typedef __attribute__((address_space(3))) void LAS;
#define GLOAD16(gp, lp) \
    __builtin_amdgcn_global_load_lds((GAS*)(gp), (LAS*)(lp), 16, 0, 0)

__global__ __launch_bounds__(256)
void moe_gate_kernel(const float* __restrict__ X,
                     const float* __restrict__ W,
                     float* __restrict__ out)
{
    // double-buffered staging (2 x (8KB A + 20KB B)) / epilogue scores (42KB)
    __shared__ union alignas(16) SM {
        struct { float As[2][TOKB * 32]; float Bs[2][NEXP * 32]; } g;
        float S[TOKB * S_S];
    } u;

    const int tid = threadIdx.x;
    const int tx  = tid & 31;      // expert lane: experts tx + 32q, q=0..4
    const int oct = tid >> 5;      // token octet: tokens 8*oct .. 8*oct+7
    const int l   = tid & 63;
    const int w   = tid >> 6;      // wave 0..3
    const int stx = tx & 7;
    const int tb  = blockIdx.x * TOKB;

    // ---- staging sources: 1KB chunk = 8 rows x 32 floats;
    //      lane l -> row (l>>3), 16B slot (l&7) ----
    const int rr = l >> 3;         // row-in-chunk
    const int sl = l & 7;          // dest slot-in-row
    // A chunks j = 2w, 2w+1 (rows 8j..8j+7), source LINEAR:
    const float* srcA[2];
    #pragma unroll
    for (int jj = 0; jj < 2; ++jj)
        srcA[jj] = X + (size_t)(tb + 8 * (2 * w + jj) + rr) * HID + 4 * sl;
    // B chunks m = 5w..5w+4 (rows e = 8m..8m+7), source slot (l&7)^(l>>3):
    const float* srcB[5];
    #pragma unroll
    for (int mm = 0; mm < 5; ++mm)
        srcB[mm] = W + (size_t)(8 * (5 * w + mm) + rr) * HID + 4 * (sl ^ rr);

    auto ISSUE = [&](int st, int b) {
        const size_t ko = (size_t)st * 32;
        #pragma unroll
        for (int jj = 0; jj < 2; ++jj)
            GLOAD16(srcA[jj] + ko, (char*)&u.g.As[b][0] + (2 * w + jj) * 1024);
        #pragma unroll
        for (int mm = 0; mm < 5; ++mm)
            GLOAD16(srcB[mm] + ko, (char*)&u.g.Bs[b][0] + (5 * w + mm) * 1024);
    };

    float acc[8][5], tacc[8][5];
    #pragma unroll
    for (int i = 0; i < 8; ++i)
        #pragma unroll
        for (int q = 0; q < 5; ++q) acc[i][q] = 0.f;

#define READQ(Aq, Bq, c) do {                                            \
        _Pragma("unroll")                                                \
        for (int i = 0; i < 8; ++i)                                      \
            Aq[i] = *(const f32x4*)(Ab + i * 32 + 4 * (c));              \
        _Pragma("unroll")                                                \
        for (int q = 0; q < 5; ++q)                                      \
            Bq[q] = *(const f32x4*)(Bb + q * (32 * 32) + 4 * ((c) ^ stx)); \
    } while (0)

#define FMAQ(Aq, Bq) do {                                                \
        _Pragma("unroll")                                                \
        for (int i = 0; i < 8; ++i)                                      \
            _Pragma("unroll")                                            \
            for (int q = 0; q < 5; ++q) {                                \
                tacc[i][q] = fmaf(Aq[i].x, Bq[q].x, tacc[i][q]);         \
                tacc[i][q] = fmaf(Aq[i].y, Bq[q].y, tacc[i][q]);         \
                tacc[i][q] = fmaf(Aq[i].z, Bq[q].z, tacc[i][q]);         \
                tacc[i][q] = fmaf(Aq[i].w, Bq[q].w, tacc[i][q]);         \
            }                                                            \
    } while (0)

    ISSUE(0, 0);

    for (int st = 0; st < NST; ++st) {
        const int b = st & 1;
        asm volatile("s_waitcnt vmcnt(0)" ::: "memory");  // st's loads landed
        __syncthreads();                                  // tile visible
        if (st + 1 < NST) ISSUE(st + 1, b ^ 1);           // prefetch in flight
                                                          //   across compute
        if (!(st & 1)) {
            #pragma unroll
            for (int i = 0; i < 8; ++i)
                #pragma unroll
                for (int q = 0; q < 5; ++q) tacc[i][q] = 0.f;  // new 64-k tile
        }

        const float* Ab = &u.g.As[b][(8 * oct) * 32];
        const float* Bb = &u.g.Bs[b][tx * 32];

        f32x4 Aq0[8], Bq0[5], Aq1[8], Bq1[5];
        READQ(Aq0, Bq0, 0);
        #pragma unroll
        for (int c = 0; c < 8; c += 2) {       // kk quads, ascending
            READQ(Aq1, Bq1, c + 1);
            FMAQ(Aq0, Bq0);
            if (c + 2 < 8) READQ(Aq0, Bq0, c + 2);
            FMAQ(Aq1, Bq1);
        }

        if (st & 1) {
            #pragma unroll
            for (int i = 0; i < 8; ++i)
                #pragma unroll
                for (int q = 0; q < 5; ++q) acc[i][q] += tacc[i][q];
        }
        // next top barrier fences buffer reuse
    }

    // ---- write logits: token 8*oct+i, expert tx+32q ----
    __syncthreads();
    #pragma unroll
    for (int i = 0; i < 8; ++i) {
        const int t = 8 * oct + i;
        #pragma unroll
        for (int q = 0; q < 5; ++q) u.S[t * S_S + tx + 32 * q] = acc[i][q];
    }
    __syncthreads();

    // ---- epilogue (round-5 verified): each of 4 waves owns 16 tokens ----
    const int lane = tid & 63;
    const int wv_  = tid >> 6;

    for (int it = 0; it < 16; ++it) {
        const int t = wv_ * 16 + it;

        float s0 = u.S[t * S_S + lane];
        float s1 = u.S[t * S_S + lane + 64];
        float s2 = (lane < 32) ? u.S[t * S_S + lane + 128] : -3.0e38f;

        float m = fmaxf(fmaxf(s0, s1), s2);
        #pragma unroll
        for (int d = 32; d >= 1; d >>= 1) m = fmaxf(m, __shfl_xor(m, d));

        float p0 = __expf(s0 - m);
        float p1 = __expf(s1 - m);
        float p2 = (lane < 32) ? __expf(s2 - m) : 0.f;
        float sum = p0 + p1 + p2;
        #pragma unroll
        for (int d = 32; d >= 1; d >>= 1) sum += __shfl_xor(sum, d);
        const float inv = 1.0f / sum;
        const float sc0 = p0 * inv, sc1 = p1 * inv, sc2 = p2 * inv;

        u.S[t * S_S + lane]      = sc0;
        u.S[t * S_S + lane + 64] = sc1;
        if (lane < 32) u.S[t * S_S + lane + 128] = sc2;
        __syncthreads();   // uniform across block (all waves loop 16x)

        float gm = -1.0f;
        if (lane < 8) {
            #pragma unroll
            for (int q = 0; q < 20; ++q) gm = fmaxf(gm, u.S[t * S_S + lane * 20 + q]);
        }
        unsigned gmask = 0u;
        {
            float gv[8];
            #pragma unroll
            for (int g = 0; g < 8; ++g) gv[g] = __shfl(gm, g);
            #pragma unroll
            for (int r = 0; r < 3; ++r) {
                int bi = 0; float bv2 = -2.0f;
                #pragma unroll
                for (int g = 0; g < 8; ++g) {
                    const bool taken = (gmask >> g) & 1u;
                    if (!taken && gv[g] > bv2) { bv2 = gv[g]; bi = g; }
                }
                gmask |= (1u << bi);
            }
        }

        float v0 = ((gmask >> (lane / 20)) & 1u) ? sc0 : 0.f;
        float v1 = ((gmask >> ((lane + 64) / 20)) & 1u) ? sc1 : 0.f;
        float v2 = (lane < 32) ? ((((gmask >> ((lane + 128) / 20)) & 1u) ? sc2 : 0.f))
                               : -1.f;

        float oIdx = 0.f, oW = 0.f;
        #pragma unroll
        for (int r = 0; r < 6; ++r) {
            float bv = v0; int bi = lane;
            if (v1 > bv) { bv = v1; bi = lane + 64; }
            if (v2 > bv) { bv = v2; bi = lane + 128; }
            #pragma unroll
            for (int d = 1; d < 64; d <<= 1) {
                const float ov = __shfl_xor(bv, d);
                const int   oi = __shfl_xor(bi, d);
                if (ov > bv || (ov == bv && oi < bi)) { bv = ov; bi = oi; }
            }
            if (lane == r) { oIdx = (float)bi; oW = bv * 16.0f; }
            if (bi == lane)            v0 = -1.f;
            else if (bi == lane + 64)  v1 = -1.f;
            else if (bi == lane + 128) v2 = -1.f;
        }

        const int tg = tb + t;
        if (lane < 6) {
            out[(size_t)tg * 6 + lane]                  = oIdx;
            out[(size_t)NT * 6 + (size_t)tg * 6 + lane] = oW;
        }
        __syncthreads();
    }
#undef READQ
#undef FMAQ
}

extern "C" void kernel_launch(void* const* d_in, const int* in_sizes, int n_in,
                              void* d_out, int out_size, void* d_ws, size_t ws_size,
                              hipStream_t stream)
{
    const float* X = (const float*)d_in[0];   // [4,4096,5120] fp32
    const float* W = (const float*)d_in[1];   // [160,5120] fp32
    float* out = (float*)d_out;               // [T*6 idx][T*6 weight] fp32

    moe_gate_kernel<<<NT / TOKB, 256, 0, stream>>>(X, W, out);
}

// Round 12
// 604.356 us; speedup vs baseline: 4.4875x; 1.1429x over previous
//
#include <hip/hip_runtime.h>

// DeepSeekV2 MoE gate — fp32 VALU GEMM, BIT-IDENTICAL arithmetic to the
// passing round-1/5/9/11 kernels (per (t,e): 80 logical 64-k tiles of
// sequential fmafs in ascending k, tile partials accumulated in kt order).
// Round-12 = round-11 machinery with the occupancy lever finally pulled:
//   - TOKB=32, grid=512 -> 2 BLOCKS/CU (8 waves/CU, 2 waves/SIMD): stalls
//     (lgkm waits, vmcnt drains, barriers) overlap with the other block's
//     FMA stream (m114). All prior rounds ran 1 wave/SIMD.
//   - thread tile 4 tok x 5 exp (256 thr); LDS/block 48KB staging + 21KB
//     epilogue union = 49152 B -> 2 blocks/CU fits 96KB; VGPR ~130.
//   - staging via global_load_lds w=16, SUBK=32 double-buffered, ONE
//     barrier + vmcnt(0) per subtile (R11-verified); B conflict-free via
//     pre-swizzled global source (src slot (l&7)^(l>>3), read slot c^(tx&7))
//   - tacc spans two subtiles = one logical 64-k tile -> R1's exact bracket
// Epilogue (softmax + grouped top-3/top-6) is round-8's TOKB=32 code verbatim.
// Outputs (float32): [0..T*6) = topk_idx as float, [T*6..2*T*6) = weight.

#define NT    16384
#define HID   5120
#define NEXP  160
#define TOKB  32
#define NST   160              // K sub-tiles of 32 dwords
#define S_S   164              // epilogue score row stride

typedef __attribute__((ext_vector_type(4))) float f32x4;

typedef const __attribute__((address_space(1))) void GAS;
typedef __attribute__((address_space(3))) void LAS;
#define GLOAD16(gp, lp) \
    __builtin_amdgcn_global_load_lds((GAS*)(gp), (LAS*)(lp), 16, 0, 0)

__global__ __launch_bounds__(256)
void moe_gate_kernel(const float* __restrict__ X,
                     const float* __restrict__ W,
                     float* __restrict__ out)
{
    // double-buffered staging (2 x (4KB A + 20KB B)) / epilogue scores (21KB)
    __shared__ union alignas(16) SM {
        struct { float As[2][TOKB * 32]; float Bs[2][NEXP * 32]; } g;
        float S[TOKB * S_S];
    } u;

    const int tid = threadIdx.x;
    const int tx  = tid & 31;      // expert lane: experts tx + 32q, q=0..4
    const int grp = tid >> 5;      // token group: tokens 4*grp .. 4*grp+3
    const int l   = tid & 63;
    const int w   = tid >> 6;      // wave 0..3
    const int stx = tx & 7;
    const int tb  = blockIdx.x * TOKB;

    // ---- staging sources: 1KB chunk = 8 rows x 32 floats;
    //      lane l -> row (l>>3), 16B slot (l&7) ----
    const int rr = l >> 3;         // row-in-chunk
    const int sl = l & 7;          // dest slot-in-row
    // A chunk j = w (rows 8w..8w+7 of the 32 tokens), source LINEAR:
    const float* srcA = X + (size_t)(tb + 8 * w + rr) * HID + 4 * sl;
    // B chunks m = 5w..5w+4 (rows e = 8m..8m+7), source slot (l&7)^(l>>3):
    const float* srcB[5];
    #pragma unroll
    for (int mm = 0; mm < 5; ++mm)
        srcB[mm] = W + (size_t)(8 * (5 * w + mm) + rr) * HID + 4 * (sl ^ rr);

    auto ISSUE = [&](int st, int b) {
        const size_t ko = (size_t)st * 32;
        GLOAD16(srcA + ko, (char*)&u.g.As[b][0] + w * 1024);
        #pragma unroll
        for (int mm = 0; mm < 5; ++mm)
            GLOAD16(srcB[mm] + ko, (char*)&u.g.Bs[b][0] + (5 * w + mm) * 1024);
    };

    float acc[4][5], tacc[4][5];
    #pragma unroll
    for (int i = 0; i < 4; ++i)
        #pragma unroll
        for (int q = 0; q < 5; ++q) acc[i][q] = 0.f;

#define READQ(Aq, Bq, c) do {                                            \
        _Pragma("unroll")                                                \
        for (int i = 0; i < 4; ++i)                                      \
            Aq[i] = *(const f32x4*)(Ab + i * 32 + 4 * (c));              \
        _Pragma("unroll")                                                \
        for (int q = 0; q < 5; ++q)                                      \
            Bq[q] = *(const f32x4*)(Bb + q * (32 * 32) + 4 * ((c) ^ stx)); \
    } while (0)

#define FMAQ(Aq, Bq) do {                                                \
        _Pragma("unroll")                                                \
        for (int i = 0; i < 4; ++i)                                      \
            _Pragma("unroll")                                            \
            for (int q = 0; q < 5; ++q) {                                \
                tacc[i][q] = fmaf(Aq[i].x, Bq[q].x, tacc[i][q]);         \
                tacc[i][q] = fmaf(Aq[i].y, Bq[q].y, tacc[i][q]);         \
                tacc[i][q] = fmaf(Aq[i].z, Bq[q].z, tacc[i][q]);         \
                tacc[i][q] = fmaf(Aq[i].w, Bq[q].w, tacc[i][q]);         \
            }                                                            \
    } while (0)

    ISSUE(0, 0);

    for (int st = 0; st < NST; ++st) {
        const int b = st & 1;
        asm volatile("s_waitcnt vmcnt(0)" ::: "memory");  // st's loads landed
        __syncthreads();                                  // tile visible
        if (st + 1 < NST) ISSUE(st + 1, b ^ 1);           // prefetch in flight
                                                          //   across compute
        if (!(st & 1)) {
            #pragma unroll
            for (int i = 0; i < 4; ++i)
                #pragma unroll
                for (int q = 0; q < 5; ++q) tacc[i][q] = 0.f;  // new 64-k tile
        }

        const float* Ab = &u.g.As[b][(4 * grp) * 32];
        const float* Bb = &u.g.Bs[b][tx * 32];

        f32x4 Aq0[4], Bq0[5], Aq1[4], Bq1[5];
        READQ(Aq0, Bq0, 0);
        #pragma unroll
        for (int c = 0; c < 8; c += 2) {       // kk quads, ascending
            READQ(Aq1, Bq1, c + 1);
            FMAQ(Aq0, Bq0);
            if (c + 2 < 8) READQ(Aq0, Bq0, c + 2);
            FMAQ(Aq1, Bq1);
        }

        if (st & 1) {
            #pragma unroll
            for (int i = 0; i < 4; ++i)
                #pragma unroll
                for (int q = 0; q < 5; ++q) acc[i][q] += tacc[i][q];
        }
        // next top barrier fences buffer reuse
    }

    // ---- write logits: token 4*grp+i, expert tx+32q ----
    __syncthreads();
    #pragma unroll
    for (int i = 0; i < 4; ++i) {
        const int t = 4 * grp + i;
        #pragma unroll
        for (int q = 0; q < 5; ++q) u.S[t * S_S + tx + 32 * q] = acc[i][q];
    }
    __syncthreads();

    // ---- epilogue (round-8 verified): each of 4 waves owns 8 tokens ----
    const int lane = tid & 63;
    const int wv_  = tid >> 6;

    for (int it = 0; it < 8; ++it) {
        const int t = wv_ * 8 + it;

        float s0 = u.S[t * S_S + lane];
        float s1 = u.S[t * S_S + lane + 64];
        float s2 = (lane < 32) ? u.S[t * S_S + lane + 128] : -3.0e38f;

        float m = fmaxf(fmaxf(s0, s1), s2);
        #pragma unroll
        for (int d = 32; d >= 1; d >>= 1) m = fmaxf(m, __shfl_xor(m, d));

        float p0 = __expf(s0 - m);
        float p1 = __expf(s1 - m);
        float p2 = (lane < 32) ? __expf(s2 - m) : 0.f;
        float sum = p0 + p1 + p2;
        #pragma unroll
        for (int d = 32; d >= 1; d >>= 1) sum += __shfl_xor(sum, d);
        const float inv = 1.0f / sum;
        const float sc0 = p0 * inv, sc1 = p1 * inv, sc2 = p2 * inv;

        u.S[t * S_S + lane]      = sc0;
        u.S[t * S_S + lane + 64] = sc1;
        if (lane < 32) u.S[t * S_S + lane + 128] = sc2;
        __syncthreads();   // uniform across block (all waves loop 8x)

        float gm = -1.0f;
        if (lane < 8) {
            #pragma unroll
            for (int q = 0; q < 20; ++q) gm = fmaxf(gm, u.S[t * S_S + lane * 20 + q]);
        }
        unsigned gmask = 0u;
        {
            float gv[8];
            #pragma unroll
            for (int g = 0; g < 8; ++g) gv[g] = __shfl(gm, g);
            #pragma unroll
            for (int r = 0; r < 3; ++r) {
                int bi = 0; float bv2 = -2.0f;
                #pragma unroll
                for (int g = 0; g < 8; ++g) {
                    const bool taken = (gmask >> g) & 1u;
                    if (!taken && gv[g] > bv2) { bv2 = gv[g]; bi = g; }
                }
                gmask |= (1u << bi);
            }
        }

        float v0 = ((gmask >> (lane / 20)) & 1u) ? sc0 : 0.f;
        float v1 = ((gmask >> ((lane + 64) / 20)) & 1u) ? sc1 : 0.f;
        float v2 = (lane < 32) ? ((((gmask >> ((lane + 128) / 20)) & 1u) ? sc2 : 0.f))
                               : -1.f;

        float oIdx = 0.f, oW = 0.f;
        #pragma unroll
        for (int r = 0; r < 6; ++r) {
            float bv = v0; int bi = lane;
            if (v1 > bv) { bv = v1; bi = lane + 64; }
            if (v2 > bv) { bv = v2; bi = lane + 128; }
            #pragma unroll
            for (int d = 1; d < 64; d <<= 1) {
                const float ov = __shfl_xor(bv, d);
                const int   oi = __shfl_xor(bi, d);
                if (ov > bv || (ov == bv && oi < bi)) { bv = ov; bi = oi; }
            }
            if (lane == r) { oIdx = (float)bi; oW = bv * 16.0f; }
            if (bi == lane)            v0 = -1.f;
            else if (bi == lane + 64)  v1 = -1.f;
            else if (bi == lane + 128) v2 = -1.f;
        }

        const int tg = tb + t;
        if (lane < 6) {
            out[(size_t)tg * 6 + lane]                  = oIdx;
            out[(size_t)NT * 6 + (size_t)tg * 6 + lane] = oW;
        }
        __syncthreads();
    }
#undef READQ
#undef FMAQ
}

extern "C" void kernel_launch(void* const* d_in, const int* in_sizes, int n_in,
                              void* d_out, int out_size, void* d_ws, size_t ws_size,
                              hipStream_t stream)
{
    const float* X = (const float*)d_in[0];   // [4,4096,5120] fp32
    const float* W = (const float*)d_in[1];   // [160,5120] fp32
    float* out = (float*)d_out;               // [T*6 idx][T*6 weight] fp32

    moe_gate_kernel<<<NT / TOKB, 256, 0, stream>>>(X, W, out);
}

// Round 13
// 572.687 us; speedup vs baseline: 4.7357x; 1.0553x over previous
//
#include <hip/hip_runtime.h>

// DeepSeekV2 MoE gate — hybrid MFMA fast path + exact fixup.
//  K0: zero flag counter (ws)
//  K1: W fp32 -> 3 bf16 planes (hi/mid/lo) in ws              (~6 us)
//  K2: bf16x3-split MFMA GEMM (R3 machinery) + fused margin-checked
//      epilogue; tokens with any decision margin < TAU are appended
//      to a ws list (device-scope atomic; set is deterministic)   (~80 us)
//  K3: fixup — for flagged tokens, recompute all 160 logits with the
//      R1-exact sequential fp32 bracket (bit-identical to the passing
//      rounds-1/5/12 kernels) + R1-exact epilogue, overwrite outputs (~20 us)
// If ws_size is too small: fall back to the R12 kernel (passed, 604 us).
// Outputs (float32): [0..T*6) = topk_idx as float, [T*6..2*T*6) = weight.

#define NT    16384
#define HID   5120
#define NEXP  160
#define PLANE (NEXP * HID)     // 819200 elems per bf16 plane
#define PL    (NEXP * 64)      // shorts per LDS plane tile
#define NKT   80               // K tiles of 64
#define TAU   3e-5f            // decision margin (score space)

typedef __attribute__((ext_vector_type(8))) short short8;
typedef __attribute__((ext_vector_type(4))) float f32x4;

__device__ __forceinline__ unsigned short f2bf(float x) {
    unsigned u = __float_as_uint(x);
    return (unsigned short)((u + 0x7FFFu + ((u >> 16) & 1u)) >> 16);   // RNE
}
__device__ __forceinline__ float bf2f(unsigned short h) {
    return __uint_as_float(((unsigned)h) << 16);
}
__device__ __forceinline__ void split3(const float* xs, short8& h8, short8& m8, short8& l8) {
    #pragma unroll
    for (int j = 0; j < 8; ++j) {
        float x = xs[j];
        unsigned short h = f2bf(x);  float r1 = x - bf2f(h);
        unsigned short m = f2bf(r1); float r2 = r1 - bf2f(m);
        unsigned short l = f2bf(r2);
        h8[j] = (short)h; m8[j] = (short)m; l8[j] = (short)l;
    }
}

// ---------------- K0: zero the flag counter ----------------
__global__ void zero_kernel(int* __restrict__ cnt) {
    if (threadIdx.x == 0 && blockIdx.x == 0) cnt[0] = 0;
}

// ---------------- K1: W -> bf16 hi/mid/lo planes ----------------
__global__ __launch_bounds__(256)
void wconv_kernel(const float* __restrict__ W, short* __restrict__ Ws) {
    int i = blockIdx.x * 256 + threadIdx.x;          // e*HID + k
    float x = W[i];
    unsigned short h = f2bf(x);  float r1 = x - bf2f(h);
    unsigned short m = f2bf(r1); float r2 = r1 - bf2f(m);
    unsigned short l = f2bf(r2);
    Ws[i] = (short)h; Ws[PLANE + i] = (short)m; Ws[2 * PLANE + i] = (short)l;
}

// ---------------- K2: MFMA GEMM + margin epilogue ----------------
// Block = 32 tokens, 256 thr (4 waves). Wave (kg,nh): kg = k-half of the
// 64-k tile, nh = expert half. (R3 machinery: validated structurally.)
__global__ __launch_bounds__(256, 2)
void moe_mfma_kernel(const float* __restrict__ X, const short* __restrict__ Ws,
                     float* __restrict__ out, int* __restrict__ cnt,
                     int* __restrict__ list)
{
    __shared__ union alignas(16) SM {
        short Bs[3 * PL];          // 61440 B (3 bf16 planes, XOR-swizzled)
        float S[32][NEXP + 4];     // epilogue scores
    } u;

    const int tid = threadIdx.x;
    const int wv  = tid >> 6;
    const int kg  = wv & 1;        // k-half of the 64-k tile
    const int nh  = wv >> 1;       // expert half (nh*80)
    const int l   = tid & 63;
    const int lr  = l & 15;        // fragment row/col
    const int lh  = l >> 4;        // k-octet group
    const int tb  = blockIdx.x * 32;
    const int srow = tid >> 3;     // staging row 0..31
    const int skc  = tid & 7;      // staging k-octet

    f32x4 acc[2][5];
    #pragma unroll
    for (int a = 0; a < 2; ++a)
        #pragma unroll
        for (int b = 0; b < 5; ++b) acc[a][b] = (f32x4){0.f, 0.f, 0.f, 0.f};

    const float* xbase0 = X + (size_t)(tb + lr) * HID + kg * 32 + lh * 8;
    const float* xbase1 = xbase0 + (size_t)16 * HID;

    short8 wst[5][3];              // prefetched W-plane slabs
    float4 ax[2][2];               // prefetched A

    auto LOADW = [&](int kt) {
        #pragma unroll
        for (int i = 0; i < 5; ++i) {
            const short* wp = Ws + (size_t)(i * 32 + srow) * HID + kt * 64 + skc * 8;
            wst[i][0] = *(const short8*)wp;
            wst[i][1] = *(const short8*)(wp + PLANE);
            wst[i][2] = *(const short8*)(wp + 2 * PLANE);
        }
    };
    auto LOADA = [&](int kt) {
        #pragma unroll
        for (int mt = 0; mt < 2; ++mt) {
            const float* xp = (mt ? xbase1 : xbase0) + kt * 64;
            ax[mt][0] = *(const float4*)xp;
            ax[mt][1] = *(const float4*)(xp + 4);
        }
    };

    LOADW(0); LOADA(0);

    for (int kt = 0; kt < NKT; ++kt) {
        __syncthreads();                       // prev tile's Bs reads done
        #pragma unroll
        for (int i = 0; i < 5; ++i) {          // stage, swizzle col ^= (row&7)<<3
            const int wr = i * 32 + srow;
            const int sw = (skc * 8) ^ ((wr & 7) << 3);
            short* bp = &u.Bs[wr * 64 + sw];
            *(short8*)bp            = wst[i][0];
            *(short8*)(bp + PL)     = wst[i][1];
            *(short8*)(bp + 2 * PL) = wst[i][2];
        }
        __syncthreads();                       // Bs[kt] ready

        if (kt + 1 < NKT) LOADW(kt + 1);

        short8 Ah[2], Am[2], Al[2];
        #pragma unroll
        for (int mt = 0; mt < 2; ++mt) {
            float xsr[8] = {ax[mt][0].x, ax[mt][0].y, ax[mt][0].z, ax[mt][0].w,
                            ax[mt][1].x, ax[mt][1].y, ax[mt][1].z, ax[mt][1].w};
            split3(xsr, Ah[mt], Am[mt], Al[mt]);
        }
        if (kt + 1 < NKT) LOADA(kt + 1);

        #pragma unroll
        for (int nt = 0; nt < 5; ++nt) {
            const int row = nh * 80 + nt * 16 + lr;
            const int sc  = (kg * 32 + lh * 8) ^ ((lr & 7) << 3);
            const short* bp = &u.Bs[row * 64 + sc];
            short8 Bh = *(const short8*)bp;
            short8 Bm = *(const short8*)(bp + PL);
            short8 Bl = *(const short8*)(bp + 2 * PL);
            #pragma unroll
            for (int mt = 0; mt < 2; ++mt) {
                f32x4 c = acc[mt][nt];         // smalls first
                c = __builtin_amdgcn_mfma_f32_16x16x32_bf16(Ah[mt], Bl, c, 0, 0, 0);
                c = __builtin_amdgcn_mfma_f32_16x16x32_bf16(Al[mt], Bh, c, 0, 0, 0);
                c = __builtin_amdgcn_mfma_f32_16x16x32_bf16(Am[mt], Bm, c, 0, 0, 0);
                c = __builtin_amdgcn_mfma_f32_16x16x32_bf16(Ah[mt], Bm, c, 0, 0, 0);
                c = __builtin_amdgcn_mfma_f32_16x16x32_bf16(Am[mt], Bh, c, 0, 0, 0);
                c = __builtin_amdgcn_mfma_f32_16x16x32_bf16(Ah[mt], Bh, c, 0, 0, 0);
                acc[mt][nt] = c;
            }
        }
    }

    // ---- combine kg halves into S (C/D: col=l&15, row=(l>>4)*4+r) ----
    __syncthreads();
    if (kg == 0) {
        #pragma unroll
        for (int mt = 0; mt < 2; ++mt)
            #pragma unroll
            for (int nt = 0; nt < 5; ++nt)
                #pragma unroll
                for (int r = 0; r < 4; ++r)
                    u.S[mt * 16 + lh * 4 + r][nh * 80 + nt * 16 + lr] = acc[mt][nt][r];
    }
    __syncthreads();
    if (kg == 1) {
        #pragma unroll
        for (int mt = 0; mt < 2; ++mt)
            #pragma unroll
            for (int nt = 0; nt < 5; ++nt)
                #pragma unroll
                for (int r = 0; r < 4; ++r)
                    u.S[mt * 16 + lh * 4 + r][nh * 80 + nt * 16 + lr] += acc[mt][nt][r];
    }
    __syncthreads();

    // ---- epilogue with decision margins: each wave owns 8 tokens ----
    const int lane = tid & 63;
    const int wv_  = tid >> 6;

    for (int it = 0; it < 8; ++it) {
        const int t = wv_ * 8 + it;

        float s0 = u.S[t][lane];
        float s1 = u.S[t][lane + 64];
        float s2 = (lane < 32) ? u.S[t][lane + 128] : -3.0e38f;

        float m = fmaxf(fmaxf(s0, s1), s2);
        #pragma unroll
        for (int d = 32; d >= 1; d >>= 1) m = fmaxf(m, __shfl_xor(m, d));

        float p0 = __expf(s0 - m);
        float p1 = __expf(s1 - m);
        float p2 = (lane < 32) ? __expf(s2 - m) : 0.f;
        float sum = p0 + p1 + p2;
        #pragma unroll
        for (int d = 32; d >= 1; d >>= 1) sum += __shfl_xor(sum, d);
        const float inv = 1.0f / sum;
        const float sc0 = p0 * inv, sc1 = p1 * inv, sc2 = p2 * inv;

        u.S[t][lane]      = sc0;
        u.S[t][lane + 64] = sc1;
        if (lane < 32) u.S[t][lane + 128] = sc2;
        __syncthreads();   // uniform across block

        float gm = -1.0f;
        if (lane < 8) {
            #pragma unroll
            for (int q = 0; q < 20; ++q) gm = fmaxf(gm, u.S[t][lane * 20 + q]);
        }
        // group top-3 + 4th value (margin): tie -> lower group index
        unsigned gmask = 0u;
        float g3 = -2.0f, g4 = -2.0f;
        {
            float gv[8];
            #pragma unroll
            for (int g = 0; g < 8; ++g) gv[g] = __shfl(gm, g);
            #pragma unroll
            for (int r = 0; r < 4; ++r) {
                int bi = 0; float bv2 = -2.0f;
                #pragma unroll
                for (int g = 0; g < 8; ++g) {
                    const bool taken = (gmask >> g) & 1u;
                    if (!taken && gv[g] > bv2) { bv2 = gv[g]; bi = g; }
                }
                if (r < 3) { gmask |= (1u << bi); if (r == 2) g3 = bv2; }
                else g4 = bv2;
            }
        }

        float v0 = ((gmask >> (lane / 20)) & 1u) ? sc0 : 0.f;
        float v1 = ((gmask >> ((lane + 64) / 20)) & 1u) ? sc1 : 0.f;
        float v2 = (lane < 32) ? ((((gmask >> ((lane + 128) / 20)) & 1u) ? sc2 : 0.f))
                               : -1.f;

        // 7 rounds of wave argmax: rounds 0..5 select, round 6 = margin probe
        float vals[7];
        float oIdx = 0.f, oW = 0.f;
        #pragma unroll
        for (int r = 0; r < 7; ++r) {
            float bv = v0; int bi = lane;
            if (v1 > bv) { bv = v1; bi = lane + 64; }
            if (v2 > bv) { bv = v2; bi = lane + 128; }
            #pragma unroll
            for (int d = 1; d < 64; d <<= 1) {
                const float ov = __shfl_xor(bv, d);
                const int   oi = __shfl_xor(bi, d);
                if (ov > bv || (ov == bv && oi < bi)) { bv = ov; bi = oi; }
            }
            vals[r] = bv;
            if (r < 6) {
                if (lane == r) { oIdx = (float)bi; oW = bv * 16.0f; }
                if (bi == lane)            v0 = -1.f;
                else if (bi == lane + 64)  v1 = -1.f;
                else if (bi == lane + 128) v2 = -1.f;
            }
        }

        float mg = g3 - g4;
        #pragma unroll
        for (int r = 0; r < 6; ++r) mg = fminf(mg, vals[r] - vals[r + 1]);

        const int tg = tb + t;
        if (lane == 0 && mg < TAU) {           // knife-edge -> exact fixup
            int ix = atomicAdd(cnt, 1);
            list[ix] = tg;
        }
        if (lane < 6) {
            out[(size_t)tg * 6 + lane]                  = oIdx;
            out[(size_t)NT * 6 + (size_t)tg * 6 + lane] = oW;
        }
        __syncthreads();
    }
}

// ---------------- K3: exact fixup for flagged tokens ----------------
// Per flagged token: recompute all 160 logits with the R1-exact bracket
// (per (t,e): 80 K-tiles, tacc zeroed, 64 sequential fmaf ascending k,
// acc += tacc in kt order) and redo the R1 epilogue. Overwrites outputs.
__global__ __launch_bounds__(256)
void fixup_kernel(const float* __restrict__ X, const float* __restrict__ W,
                  float* __restrict__ out, const int* __restrict__ cnt,
                  const int* __restrict__ list)
{
    __shared__ float xs[HID];          // 20 KB token row
    __shared__ float S[NEXP + 4];

    const int tid = threadIdx.x;
    const int n = cnt[0];

    for (int ii = blockIdx.x; ii < n; ii += gridDim.x) {
        const int t = list[ii];
        __syncthreads();               // xs/S reuse fence across iterations
        for (int j = tid; j < HID / 4; j += 256)
            ((float4*)xs)[j] = ((const float4*)(X + (size_t)t * HID))[j];
        __syncthreads();

        if (tid < NEXP) {              // thread = expert; R1-exact chain
            const float* wr = W + (size_t)tid * HID;
            float acc = 0.f;
            for (int kt = 0; kt < NKT; ++kt) {
                float tacc = 0.f;
                #pragma unroll
                for (int c = 0; c < 16; ++c) {
                    const float4 xq = *(const float4*)&xs[kt * 64 + 4 * c];
                    const float4 wq = *(const float4*)(wr + kt * 64 + 4 * c);
                    tacc = fmaf(xq.x, wq.x, tacc);
                    tacc = fmaf(xq.y, wq.y, tacc);
                    tacc = fmaf(xq.z, wq.z, tacc);
                    tacc = fmaf(xq.w, wq.w, tacc);
                }
                acc += tacc;
            }
            S[tid] = acc;
        }
        __syncthreads();

        if (tid < 64) {                // R1-exact softmax (wave 0)
            const int lane = tid;
            float s0 = S[lane];
            float s1 = S[lane + 64];
            float s2 = (lane < 32) ? S[lane + 128] : -3.0e38f;
            float m = fmaxf(fmaxf(s0, s1), s2);
            #pragma unroll
            for (int d = 32; d >= 1; d >>= 1) m = fmaxf(m, __shfl_xor(m, d));
            float p0 = __expf(s0 - m);
            float p1 = __expf(s1 - m);
            float p2 = (lane < 32) ? __expf(s2 - m) : 0.f;
            float sum = p0 + p1 + p2;
            #pragma unroll
            for (int d = 32; d >= 1; d >>= 1) sum += __shfl_xor(sum, d);
            const float inv = 1.0f / sum;
            S[lane]      = p0 * inv;
            S[lane + 64] = p1 * inv;
            if (lane < 32) S[lane + 128] = p2 * inv;
        }
        __syncthreads();

        if (tid < 64) {                // R1-exact grouped top-k (wave 0)
            const int lane = tid;
            const float sc0 = S[lane];
            const float sc1 = S[lane + 64];
            const float sc2 = (lane < 32) ? S[lane + 128] : 0.f;
            float gm = -1.0f;
            if (lane < 8) {
                #pragma unroll
                for (int q = 0; q < 20; ++q) gm = fmaxf(gm, S[lane * 20 + q]);
            }
            unsigned gmask = 0u;
            {
                float gv[8];
                #pragma unroll
                for (int g = 0; g < 8; ++g) gv[g] = __shfl(gm, g);
                #pragma unroll
                for (int r = 0; r < 3; ++r) {
                    int bi = 0; float bv2 = -2.0f;
                    #pragma unroll
                    for (int g = 0; g < 8; ++g) {
                        const bool taken = (gmask >> g) & 1u;
                        if (!taken && gv[g] > bv2) { bv2 = gv[g]; bi = g; }
                    }
                    gmask |= (1u << bi);
                }
            }
            float v0 = ((gmask >> (lane / 20)) & 1u) ? sc0 : 0.f;
            float v1 = ((gmask >> ((lane + 64) / 20)) & 1u) ? sc1 : 0.f;
            float v2 = (lane < 32) ? ((((gmask >> ((lane + 128) / 20)) & 1u) ? sc2 : 0.f))
                                   : -1.f;
            float oIdx = 0.f, oW = 0.f;
            #pragma unroll
            for (int r = 0; r < 6; ++r) {
                float bv = v0; int bi = lane;
                if (v1 > bv) { bv = v1; bi = lane + 64; }
                if (v2 > bv) { bv = v2; bi = lane + 128; }
                #pragma unroll
                for (int d = 1; d < 64; d <<= 1) {
                    const float ov = __shfl_xor(bv, d);
                    const int   oi = __shfl_xor(bi, d);
                    if (ov > bv || (ov == bv && oi < bi)) { bv = ov; bi = oi; }
                }
                if (lane == r) { oIdx = (float)bi; oW = bv * 16.0f; }
                if (bi == lane)            v0 = -1.f;
                else if (bi == lane + 64)  v1 = -1.f;
                else if (bi == lane + 128) v2 = -1.f;
            }
            if (lane < 6) {
                out[(size_t)t * 6 + lane]                  = oIdx;
                out[(size_t)NT * 6 + (size_t)t * 6 + lane] = oW;
            }
        }
    }
}

// ---------------- Fallback: round-12 kernel (passed, 604 us) ----------------
#define FB_TOKB 32
#define FB_NST  160
#define FB_S_S  164

typedef const __attribute__((address_space(1))) void GAS;
typedef __attribute__((address_space(3))) void LAS;
#define GLOAD16(gp, lp) \
    __builtin_amdgcn_global_load_lds((GAS*)(gp), (LAS*)(lp), 16, 0, 0)

__global__ __launch_bounds__(256)
void fb_kernel(const float* __restrict__ X, const float* __restrict__ W,
               float* __restrict__ out)
{
    __shared__ union alignas(16) SM {
        struct { float As[2][FB_TOKB * 32]; float Bs[2][NEXP * 32]; } g;
        float S[FB_TOKB * FB_S_S];
    } u;

    const int tid = threadIdx.x;
    const int tx  = tid & 31;
    const int grp = tid >> 5;
    const int l   = tid & 63;
    const int w   = tid >> 6;
    const int stx = tx & 7;
    const int tb  = blockIdx.x * FB_TOKB;

    const int rr = l >> 3;
    const int sl = l & 7;
    const float* srcA = X + (size_t)(tb + 8 * w + rr) * HID + 4 * sl;
    const float* srcB[5];
    #pragma unroll
    for (int mm = 0; mm < 5; ++mm)
        srcB[mm] = W + (size_t)(8 * (5 * w + mm) + rr) * HID + 4 * (sl ^ rr);

    auto ISSUE = [&](int st, int b) {
        const size_t ko = (size_t)st * 32;
        GLOAD16(srcA + ko, (char*)&u.g.As[b][0] + w * 1024);
        #pragma unroll
        for (int mm = 0; mm < 5; ++mm)
            GLOAD16(srcB[mm] + ko, (char*)&u.g.Bs[b][0] + (5 * w + mm) * 1024);
    };

    float acc[4][5], tacc[4][5];
    #pragma unroll
    for (int i = 0; i < 4; ++i)
        #pragma unroll
        for (int q = 0; q < 5; ++q) acc[i][q] = 0.f;

#define FB_READQ(Aq, Bq, c) do {                                         \
        _Pragma("unroll")                                                \
        for (int i = 0; i < 4; ++i)                                      \
            Aq[i] = *(const f32x4*)(Ab + i * 32 + 4 * (c));              \
        _Pragma("unroll")                                                \
        for (int q = 0; q < 5; ++q)                                      \
            Bq[q] = *(const f32x4*)(Bb + q * (32 * 32) + 4 * ((c) ^ stx)); \
    } while (0)

#define FB_FMAQ(Aq, Bq) do {                                             \
        _Pragma("unroll")                                                \
        for (int i = 0; i < 4; ++i)                                      \
            _Pragma("unroll")                                            \
            for (int q = 0; q < 5; ++q) {                                \
                tacc[i][q] = fmaf(Aq[i].x, Bq[q].x, tacc[i][q]);         \
                tacc[i][q] = fmaf(Aq[i].y, Bq[q].y, tacc[i][q]);         \
                tacc[i][q] = fmaf(Aq[i].z, Bq[q].z, tacc[i][q]);         \
                tacc[i][q] = fmaf(Aq[i].w, Bq[q].w, tacc[i][q]);         \
            }                                                            \
    } while (0)

    ISSUE(0, 0);

    for (int st = 0; st < FB_NST; ++st) {
        const int b = st & 1;
        asm volatile("s_waitcnt vmcnt(0)" ::: "memory");
        __syncthreads();
        if (st + 1 < FB_NST) ISSUE(st + 1, b ^ 1);

        if (!(st & 1)) {
            #pragma unroll
            for (int i = 0; i < 4; ++i)
                #pragma unroll
                for (int q = 0; q < 5; ++q) tacc[i][q] = 0.f;
        }

        const float* Ab = &u.g.As[b][(4 * grp) * 32];
        const float* Bb = &u.g.Bs[b][tx * 32];

        f32x4 Aq0[4], Bq0[5], Aq1[4], Bq1[5];
        FB_READQ(Aq0, Bq0, 0);
        #pragma unroll
        for (int c = 0; c < 8; c += 2) {
            FB_READQ(Aq1, Bq1, c + 1);
            FB_FMAQ(Aq0, Bq0);
            if (c + 2 < 8) FB_READQ(Aq0, Bq0, c + 2);
            FB_FMAQ(Aq1, Bq1);
        }

        if (st & 1) {
            #pragma unroll
            for (int i = 0; i < 4; ++i)
                #pragma unroll
                for (int q = 0; q < 5; ++q) acc[i][q] += tacc[i][q];
        }
    }

    __syncthreads();
    #pragma unroll
    for (int i = 0; i < 4; ++i) {
        const int t = 4 * grp + i;
        #pragma unroll
        for (int q = 0; q < 5; ++q) u.S[t * FB_S_S + tx + 32 * q] = acc[i][q];
    }
    __syncthreads();

    const int lane = tid & 63;
    const int wv_  = tid >> 6;

    for (int it = 0; it < 8; ++it) {
        const int t = wv_ * 8 + it;

        float s0 = u.S[t * FB_S_S + lane];
        float s1 = u.S[t * FB_S_S + lane + 64];
        float s2 = (lane < 32) ? u.S[t * FB_S_S + lane + 128] : -3.0e38f;

        float m = fmaxf(fmaxf(s0, s1), s2);
        #pragma unroll
        for (int d = 32; d >= 1; d >>= 1) m = fmaxf(m, __shfl_xor(m, d));

        float p0 = __expf(s0 - m);
        float p1 = __expf(s1 - m);
        float p2 = (lane < 32) ? __expf(s2 - m) : 0.f;
        float sum = p0 + p1 + p2;
        #pragma unroll
        for (int d = 32; d >= 1; d >>= 1) sum += __shfl_xor(sum, d);
        const float inv = 1.0f / sum;
        const float sc0 = p0 * inv, sc1 = p1 * inv, sc2 = p2 * inv;

        u.S[t * FB_S_S + lane]      = sc0;
        u.S[t * FB_S_S + lane + 64] = sc1;
        if (lane < 32) u.S[t * FB_S_S + lane + 128] = sc2;
        __syncthreads();

        float gm = -1.0f;
        if (lane < 8) {
            #pragma unroll
            for (int q = 0; q < 20; ++q) gm = fmaxf(gm, u.S[t * FB_S_S + lane * 20 + q]);
        }
        unsigned gmask = 0u;
        {
            float gv[8];
            #pragma unroll
            for (int g = 0; g < 8; ++g) gv[g] = __shfl(gm, g);
            #pragma unroll
            for (int r = 0; r < 3; ++r) {
                int bi = 0; float bv2 = -2.0f;
                #pragma unroll
                for (int g = 0; g < 8; ++g) {
                    const bool taken = (gmask >> g) & 1u;
                    if (!taken && gv[g] > bv2) { bv2 = gv[g]; bi = g; }
                }
                gmask |= (1u << bi);
            }
        }

        float v0 = ((gmask >> (lane / 20)) & 1u) ? sc0 : 0.f;
        float v1 = ((gmask >> ((lane + 64) / 20)) & 1u) ? sc1 : 0.f;
        float v2 = (lane < 32) ? ((((gmask >> ((lane + 128) / 20)) & 1u) ? sc2 : 0.f))
                               : -1.f;

        float oIdx = 0.f, oW = 0.f;
        #pragma unroll
        for (int r = 0; r < 6; ++r) {
            float bv = v0; int bi = lane;
            if (v1 > bv) { bv = v1; bi = lane + 64; }
            if (v2 > bv) { bv = v2; bi = lane + 128; }
            #pragma unroll
            for (int d = 1; d < 64; d <<= 1) {
                const float ov = __shfl_xor(bv, d);
                const int   oi = __shfl_xor(bi, d);
                if (ov > bv || (ov == bv && oi < bi)) { bv = ov; bi = oi; }
            }
            if (lane == r) { oIdx = (float)bi; oW = bv * 16.0f; }
            if (bi == lane)            v0 = -1.f;
            else if (bi == lane + 64)  v1 = -1.f;
            else if (bi == lane + 128) v2 = -1.f;
        }

        const int tg = tb + t;
        if (lane < 6) {
            out[(size_t)tg * 6 + lane]                  = oIdx;
            out[(size_t)NT * 6 + (size_t)tg * 6 + lane] = oW;
        }
        __syncthreads();
    }
#undef FB_READQ
#undef FB_FMAQ
}

extern "C" void kernel_launch(void* const* d_in, const int* in_sizes, int n_in,
                              void* d_out, int out_size, void* d_ws, size_t ws_size,
                              hipStream_t stream)
{
    const float* X = (const float*)d_in[0];   // [4,4096,5120] fp32
    const float* W = (const float*)d_in[1];   // [160,5120] fp32
    float* out = (float*)d_out;

    const size_t need = (size_t)3 * PLANE * 2 + 4 + (size_t)NT * 4;  // ~4.98 MB
    if (ws_size >= need) {
        short* Ws = (short*)d_ws;
        int* cnt  = (int*)((char*)d_ws + (size_t)3 * PLANE * 2);
        int* list = cnt + 1;
        zero_kernel   <<<1,           1,   0, stream>>>(cnt);
        wconv_kernel  <<<PLANE / 256, 256, 0, stream>>>(W, Ws);
        moe_mfma_kernel<<<NT / 32,    256, 0, stream>>>(X, Ws, out, cnt, list);
        fixup_kernel  <<<256,         256, 0, stream>>>(X, W, out, cnt, list);
    } else {
        fb_kernel<<<NT / FB_TOKB, 256, 0, stream>>>(X, W, out);
    }
}